// Round 2
// baseline (754.262 us; speedup 1.0000x reference)
//
#include <hip/hip_runtime.h>
#include <math.h>

// Geometry (fixed by the reference)
#define WD 64
#define TD 8192
#define NT 131072           // 16 * 8192 rows
#define KB 2048
// Output layout (float32, concatenated): x_l [NT], x_d [NT*WD], commit, fit, prenorm
#define OFF_XL 0
#define OFF_XD NT
#define OFF_SC (NT + NT * WD)

typedef const float __attribute__((address_space(4)))* cbp_t;

// numpy pairwise_sum (scalar 8-accumulator path, n=64, contiguous) of PRE-ROUNDED
// squares: r[j] = a[j]^2; r[j] += a[8i+j]^2; combine ((r0+r1)+(r2+r3))+((r4+r5)+(r6+r7)).
// All ops via *_rn intrinsics so the compiler cannot contract or reassociate.
template <typename P>
__device__ __forceinline__ float np_sumsq64(P a) {
  float r0 = __fmul_rn(a[0], a[0]);
  float r1 = __fmul_rn(a[1], a[1]);
  float r2 = __fmul_rn(a[2], a[2]);
  float r3 = __fmul_rn(a[3], a[3]);
  float r4 = __fmul_rn(a[4], a[4]);
  float r5 = __fmul_rn(a[5], a[5]);
  float r6 = __fmul_rn(a[6], a[6]);
  float r7 = __fmul_rn(a[7], a[7]);
#pragma unroll
  for (int i = 8; i < 64; i += 8) {
    r0 = __fadd_rn(r0, __fmul_rn(a[i + 0], a[i + 0]));
    r1 = __fadd_rn(r1, __fmul_rn(a[i + 1], a[i + 1]));
    r2 = __fadd_rn(r2, __fmul_rn(a[i + 2], a[i + 2]));
    r3 = __fadd_rn(r3, __fmul_rn(a[i + 3], a[i + 3]));
    r4 = __fadd_rn(r4, __fmul_rn(a[i + 4], a[i + 4]));
    r5 = __fadd_rn(r5, __fmul_rn(a[i + 5], a[i + 5]));
    r6 = __fadd_rn(r6, __fmul_rn(a[i + 6], a[i + 6]));
    r7 = __fadd_rn(r7, __fmul_rn(a[i + 7], a[i + 7]));
  }
  float t01 = __fadd_rn(r0, r1);
  float t23 = __fadd_rn(r2, r3);
  float t45 = __fadd_rn(r4, r5);
  float t67 = __fadd_rn(r6, r7);
  return __fadd_rn(__fadd_rn(t01, t23), __fadd_rn(t45, t67));
}

__global__ __launch_bounds__(256)
void vq_main(const float* __restrict__ x, const float* __restrict__ kcb,
             float* __restrict__ out, double* __restrict__ red) {
  __shared__ float kn2[KB];     // np-exact ||k_j||^2 (fp32)
  __shared__ double sred[16];

  const int tid = threadIdx.x;
  const int row = blockIdx.x * 256 + tid;
  const int n = row >> 13;
  const int t = row & (TD - 1);

  for (int c = tid; c < KB; c += 256) kn2[c] = np_sumsq64(kcb + c * WD);
  __syncthreads();

  // Load row (lane-coalesced over t)
  float xv[WD];
  const float* xr = x + ((size_t)n * WD) * TD + t;
#pragma unroll
  for (int w = 0; w < WD; ++w) xv[w] = xr[(size_t)w * TD];

  // np-exact ||x_i||^2 (fp32, pairwise-8 of rounded squares)
  const float s = np_sumsq64(xv);

  // prenorm partials (fp64 — 2% threshold, no need for bit-exactness)
  double xsum = 0.0, xsumsq = 0.0;
#pragma unroll
  for (int w = 0; w < WD; ++w) {
    double xd = (double)xv[w];
    xsum += xd;
    xsumsq = fma(xd, xd, xsumsq);
  }

  // Main loop: bit-exact np fp32 dist, first-min argmin.
  // g = sequential fp32 FMA chain over k (sgemm order); d = (s - 2g) + n_j.
  cbp_t kc = (cbp_t)(unsigned long long)kcb;
  float best = INFINITY;
  int bidx = 0;
  for (int j = 0; j < KB; j += 2) {
    cbp_t ka = kc + (size_t)j * WD;
    cbp_t kb = ka + WD;
    float g0 = 0.f, g1 = 0.f;
#pragma unroll
    for (int w = 0; w < WD; ++w) {
      g0 = __fmaf_rn(xv[w], ka[w], g0);
      g1 = __fmaf_rn(xv[w], kb[w], g1);
    }
    float d0 = __fadd_rn(__fsub_rn(s, __fmul_rn(2.0f, g0)), kn2[j]);
    float d1 = __fadd_rn(__fsub_rn(s, __fmul_rn(2.0f, g1)), kn2[j + 1]);
    bool c0 = d0 < best;                    // strict <  => first-index tie-break
    best = c0 ? d0 : best;
    bidx = c0 ? j : bidx;
    bool c1 = d1 < best;
    best = c1 ? d1 : best;
    bidx = c1 ? (j + 1) : bidx;
  }

  // Outputs
  out[OFF_XL + row] = (float)bidx;

  const float* kbr = kcb + (size_t)bidx * WD;
  float* xo = out + OFF_XD + ((size_t)n * WD) * TD + t;
  double commit = 0.0;
#pragma unroll
  for (int w = 0; w < WD; ++w) {
    float kw = kbr[w];
    float diff = __fsub_rn(kw, xv[w]);           // fp32 like reference
    commit = fma((double)diff, (double)diff, commit);
    xo[(size_t)w * TD] = __fadd_rn(xv[w], diff); // straight-through: xf + (x_d - xf)
  }

  // Block reduction of 4 fp64 values
  double v0 = xsum, v1 = xsumsq, v2 = (double)best, v3 = commit;
#pragma unroll
  for (int off = 32; off > 0; off >>= 1) {
    v0 += __shfl_down(v0, off, 64);
    v1 += __shfl_down(v1, off, 64);
    v2 += __shfl_down(v2, off, 64);
    v3 += __shfl_down(v3, off, 64);
  }
  if ((tid & 63) == 0) {
    int wv = tid >> 6;
    sred[wv * 4 + 0] = v0;
    sred[wv * 4 + 1] = v1;
    sred[wv * 4 + 2] = v2;
    sred[wv * 4 + 3] = v3;
  }
  __syncthreads();
  if (tid == 0) {
    double a0 = 0, a1 = 0, a2 = 0, a3 = 0;
#pragma unroll
    for (int w2 = 0; w2 < 4; ++w2) {
      a0 += sred[w2 * 4 + 0];
      a1 += sred[w2 * 4 + 1];
      a2 += sred[w2 * 4 + 2];
      a3 += sred[w2 * 4 + 3];
    }
    atomicAdd(&red[0], a0);
    atomicAdd(&red[1], a1);
    atomicAdd(&red[2], a2);
    atomicAdd(&red[3], a3);
  }
}

__global__ void vq_final(const double* __restrict__ red, float* __restrict__ out) {
  double sum = red[0], sumsq = red[1];
  double mean = sum / 8388608.0;
  double ss = sumsq - sum * mean;
  if (ss < 0.0) ss = 0.0;
  out[OFF_SC + 0] = (float)(red[3] / 8388608.0);       // commit_loss
  out[OFF_SC + 1] = (float)(red[2] / 131072.0);        // fit
  out[OFF_SC + 2] = (float)sqrt(ss / 8388608.0);       // prenorm
}

extern "C" void kernel_launch(void* const* d_in, const int* in_sizes, int n_in,
                              void* d_out, int out_size, void* d_ws, size_t ws_size,
                              hipStream_t stream) {
  const float* x = (const float*)d_in[0];
  const float* k = (const float*)d_in[1];
  float* out = (float*)d_out;
  double* red = (double*)d_ws;

  hipMemsetAsync(d_ws, 0, 4 * sizeof(double), stream);
  vq_main<<<NT / 256, 256, 0, stream>>>(x, k, out, red);
  vq_final<<<1, 1, 0, stream>>>(red, out);
}

// Round 3
// 714.375 us; speedup vs baseline: 1.0558x; 1.0558x over previous
//
#include <hip/hip_runtime.h>
#include <math.h>

// Geometry (fixed by the reference)
#define WD 64
#define TD 8192
#define NT 131072           // 16 * 8192 rows
#define KB 2048
// Output layout (float32, concatenated): x_l [NT], x_d [NT*WD], commit, fit, prenorm
#define OFF_XL 0
#define OFF_XD NT
#define OFF_SC (NT + NT * WD)

typedef const float __attribute__((address_space(4)))* cbp_t;

// numpy pairwise_sum (scalar 8-accumulator path, n=64, contiguous) of PRE-ROUNDED
// squares. All ops via *_rn intrinsics: no contraction/reassociation allowed.
__device__ __forceinline__ float np_sumsq64_arr(const float (&a)[WD]) {
  float r0 = __fmul_rn(a[0], a[0]);
  float r1 = __fmul_rn(a[1], a[1]);
  float r2 = __fmul_rn(a[2], a[2]);
  float r3 = __fmul_rn(a[3], a[3]);
  float r4 = __fmul_rn(a[4], a[4]);
  float r5 = __fmul_rn(a[5], a[5]);
  float r6 = __fmul_rn(a[6], a[6]);
  float r7 = __fmul_rn(a[7], a[7]);
#pragma unroll
  for (int i = 8; i < 64; i += 8) {
    r0 = __fadd_rn(r0, __fmul_rn(a[i + 0], a[i + 0]));
    r1 = __fadd_rn(r1, __fmul_rn(a[i + 1], a[i + 1]));
    r2 = __fadd_rn(r2, __fmul_rn(a[i + 2], a[i + 2]));
    r3 = __fadd_rn(r3, __fmul_rn(a[i + 3], a[i + 3]));
    r4 = __fadd_rn(r4, __fmul_rn(a[i + 4], a[i + 4]));
    r5 = __fadd_rn(r5, __fmul_rn(a[i + 5], a[i + 5]));
    r6 = __fadd_rn(r6, __fmul_rn(a[i + 6], a[i + 6]));
    r7 = __fadd_rn(r7, __fmul_rn(a[i + 7], a[i + 7]));
  }
  float t01 = __fadd_rn(r0, r1);
  float t23 = __fadd_rn(r2, r3);
  float t45 = __fadd_rn(r4, r5);
  float t67 = __fadd_rn(r6, r7);
  return __fadd_rn(__fadd_rn(t01, t23), __fadd_rn(t45, t67));
}

__device__ __forceinline__ float np_sumsq64_ptr(const float* a) {
  float r0 = __fmul_rn(a[0], a[0]);
  float r1 = __fmul_rn(a[1], a[1]);
  float r2 = __fmul_rn(a[2], a[2]);
  float r3 = __fmul_rn(a[3], a[3]);
  float r4 = __fmul_rn(a[4], a[4]);
  float r5 = __fmul_rn(a[5], a[5]);
  float r6 = __fmul_rn(a[6], a[6]);
  float r7 = __fmul_rn(a[7], a[7]);
#pragma unroll
  for (int i = 8; i < 64; i += 8) {
    r0 = __fadd_rn(r0, __fmul_rn(a[i + 0], a[i + 0]));
    r1 = __fadd_rn(r1, __fmul_rn(a[i + 1], a[i + 1]));
    r2 = __fadd_rn(r2, __fmul_rn(a[i + 2], a[i + 2]));
    r3 = __fadd_rn(r3, __fmul_rn(a[i + 3], a[i + 3]));
    r4 = __fadd_rn(r4, __fmul_rn(a[i + 4], a[i + 4]));
    r5 = __fadd_rn(r5, __fmul_rn(a[i + 5], a[i + 5]));
    r6 = __fadd_rn(r6, __fmul_rn(a[i + 6], a[i + 6]));
    r7 = __fadd_rn(r7, __fmul_rn(a[i + 7], a[i + 7]));
  }
  float t01 = __fadd_rn(r0, r1);
  float t23 = __fadd_rn(r2, r3);
  float t45 = __fadd_rn(r4, r5);
  float t67 = __fadd_rn(r6, r7);
  return __fadd_rn(__fadd_rn(t01, t23), __fadd_rn(t45, t67));
}

// min 2 waves/SIMD: grid is 2 blocks/CU (= 2 waves/SIMD) by construction, so
// this costs nothing and raises the VGPR cap to 256 -> xv[64] stays resident.
// (Round 2's __launch_bounds__(256) gave VGPR_Count=52: xv spilled to scratch.)
__global__ __launch_bounds__(256, 2)
void vq_main(const float* __restrict__ x, const float* __restrict__ kcb,
             float* __restrict__ out, double* __restrict__ red) {
  __shared__ float kn2[KB];     // np-exact ||k_j||^2 (fp32)
  __shared__ double sred[16];

  const int tid = threadIdx.x;
  const int row = blockIdx.x * 256 + tid;
  const int n = row >> 13;
  const int t = row & (TD - 1);

  for (int c = tid; c < KB; c += 256) kn2[c] = np_sumsq64_ptr(kcb + c * WD);
  __syncthreads();

  // Load row (lane-coalesced over t)
  float xv[WD];
  const float* xr = x + ((size_t)n * WD) * TD + t;
#pragma unroll
  for (int w = 0; w < WD; ++w) xv[w] = xr[(size_t)w * TD];

  // np-exact ||x_i||^2
  const float s = np_sumsq64_arr(xv);

  // prenorm partials (fp64 — scalar thresholds are ~2%, fp64 drift is fine)
  double xsum = 0.0, xsumsq = 0.0;
#pragma unroll
  for (int w = 0; w < WD; ++w) {
    double xd = (double)xv[w];
    xsum += xd;
    xsumsq = fma(xd, xd, xsumsq);
  }

  // Main loop: bit-exact np fp32 dist, first-min argmin.
  // 4 codes/iter = 4 independent sequential FMA chains (sgemm order per chain).
  // Codebook reads are wave-uniform addrspace(4) -> s_load; FMAs are
  // v_fmac_f32 vdst, sgpr, vgpr: one issue slot per FMA, scalar pipe in parallel.
  cbp_t kc = (cbp_t)(unsigned long long)kcb;
  float best = INFINITY;
  int bidx = 0;
  for (int j = 0; j < KB; j += 4) {
    cbp_t k0 = kc + (size_t)j * WD;
    cbp_t k1 = k0 + WD;
    cbp_t k2 = k0 + 2 * WD;
    cbp_t k3 = k0 + 3 * WD;
    float g0 = 0.f, g1 = 0.f, g2 = 0.f, g3 = 0.f;
#pragma unroll
    for (int w = 0; w < WD; ++w) {
      float xw = xv[w];
      g0 = __fmaf_rn(xw, k0[w], g0);
      g1 = __fmaf_rn(xw, k1[w], g1);
      g2 = __fmaf_rn(xw, k2[w], g2);
      g3 = __fmaf_rn(xw, k3[w], g3);
    }
    float d0 = __fadd_rn(__fsub_rn(s, __fmul_rn(2.0f, g0)), kn2[j]);
    float d1 = __fadd_rn(__fsub_rn(s, __fmul_rn(2.0f, g1)), kn2[j + 1]);
    float d2 = __fadd_rn(__fsub_rn(s, __fmul_rn(2.0f, g2)), kn2[j + 2]);
    float d3 = __fadd_rn(__fsub_rn(s, __fmul_rn(2.0f, g3)), kn2[j + 3]);
    // strictly in index order, strict <  => first-index tie-break
    bool c0 = d0 < best; best = c0 ? d0 : best; bidx = c0 ? j     : bidx;
    bool c1 = d1 < best; best = c1 ? d1 : best; bidx = c1 ? j + 1 : bidx;
    bool c2 = d2 < best; best = c2 ? d2 : best; bidx = c2 ? j + 2 : bidx;
    bool c3 = d3 < best; best = c3 ? d3 : best; bidx = c3 ? j + 3 : bidx;
  }

  // Outputs
  out[OFF_XL + row] = (float)bidx;

  const float* kbr = kcb + (size_t)bidx * WD;
  float* xo = out + OFF_XD + ((size_t)n * WD) * TD + t;
  double commit = 0.0;
#pragma unroll
  for (int w = 0; w < WD; ++w) {
    float kw = kbr[w];
    float diff = __fsub_rn(kw, xv[w]);           // fp32 like reference
    commit = fma((double)diff, (double)diff, commit);
    xo[(size_t)w * TD] = __fadd_rn(xv[w], diff); // straight-through: xf + (x_d - xf)
  }

  // Block reduction of 4 fp64 values
  double v0 = xsum, v1 = xsumsq, v2 = (double)best + (double)xsumsq * 0.0, v3 = commit;
  v2 = (double)best;
#pragma unroll
  for (int off = 32; off > 0; off >>= 1) {
    v0 += __shfl_down(v0, off, 64);
    v1 += __shfl_down(v1, off, 64);
    v2 += __shfl_down(v2, off, 64);
    v3 += __shfl_down(v3, off, 64);
  }
  if ((tid & 63) == 0) {
    int wv = tid >> 6;
    sred[wv * 4 + 0] = v0;
    sred[wv * 4 + 1] = v1;
    sred[wv * 4 + 2] = v2;
    sred[wv * 4 + 3] = v3;
  }
  __syncthreads();
  if (tid == 0) {
    double a0 = 0, a1 = 0, a2 = 0, a3 = 0;
#pragma unroll
    for (int w2 = 0; w2 < 4; ++w2) {
      a0 += sred[w2 * 4 + 0];
      a1 += sred[w2 * 4 + 1];
      a2 += sred[w2 * 4 + 2];
      a3 += sred[w2 * 4 + 3];
    }
    atomicAdd(&red[0], a0);
    atomicAdd(&red[1], a1);
    atomicAdd(&red[2], a2);
    atomicAdd(&red[3], a3);
  }
}

__global__ void vq_final(const double* __restrict__ red, float* __restrict__ out) {
  double sum = red[0], sumsq = red[1];
  double mean = sum / 8388608.0;
  double ss = sumsq - sum * mean;
  if (ss < 0.0) ss = 0.0;
  out[OFF_SC + 0] = (float)(red[3] / 8388608.0);       // commit_loss
  out[OFF_SC + 1] = (float)(red[2] / 131072.0);        // fit
  out[OFF_SC + 2] = (float)sqrt(ss / 8388608.0);       // prenorm
}

extern "C" void kernel_launch(void* const* d_in, const int* in_sizes, int n_in,
                              void* d_out, int out_size, void* d_ws, size_t ws_size,
                              hipStream_t stream) {
  const float* x = (const float*)d_in[0];
  const float* k = (const float*)d_in[1];
  float* out = (float*)d_out;
  double* red = (double*)d_ws;

  hipMemsetAsync(d_ws, 0, 4 * sizeof(double), stream);
  vq_main<<<NT / 256, 256, 0, stream>>>(x, k, out, red);
  vq_final<<<1, 1, 0, stream>>>(red, out);
}